// Round 4
// baseline (101.129 us; speedup 1.0000x reference)
//
#include <hip/hip_runtime.h>
#include <stdint.h>

#define IN_F   4096   // output width / weight cols
#define OUT_F  4096   // x width / weight rows
#define BATCH  8192
#define CHUNKS 128
#define ROWS_PER_CHUNK (OUT_F / CHUNKS)   // 32
#define ROWS_PER_BLOCK 4                  // gather rows per block

__device__ __forceinline__ uint32_t fkey(float v) {
    // monotone float -> uint mapping (order-preserving for all finite values)
    uint32_t u = __float_as_uint(v);
    return (u & 0x80000000u) ? ~u : (u | 0x80000000u);
}

// A1: partial column-argmax over a 32-row chunk (R2-proven config).
// grid (4, 128), block 256. Each thread owns 4 adjacent columns (float4 loads).
__global__ __launch_bounds__(256) void argmax_partial(
        const float* __restrict__ w,
        unsigned long long* __restrict__ part) {
    int c4 = blockIdx.x * 256 + threadIdx.x;      // float4-column index [0, 1024)
    int r0 = blockIdx.y * ROWS_PER_CHUNK;
    const float4* w4 = (const float4*)w;
    float b0 = -INFINITY, b1 = -INFINITY, b2 = -INFINITY, b3 = -INFINITY;
    int i0 = 0, i1 = 0, i2 = 0, i3 = 0;
    #pragma unroll 8
    for (int k = 0; k < ROWS_PER_CHUNK; ++k) {
        int r = r0 + k;
        float4 v = w4[(size_t)r * (IN_F / 4) + c4];
        if (v.x > b0) { b0 = v.x; i0 = r; }       // '>' keeps FIRST occurrence
        if (v.y > b1) { b1 = v.y; i1 = r; }
        if (v.z > b2) { b2 = v.z; i2 = r; }
        if (v.w > b3) { b3 = v.w; i3 = r; }
    }
    size_t base = (size_t)blockIdx.y * IN_F + (size_t)c4 * 4;
    // pack: key in high 32, ~idx in low 32 -> u64 max == (max val, then min idx)
    part[base + 0] = ((unsigned long long)fkey(b0) << 32) | (uint32_t)(~i0);
    part[base + 1] = ((unsigned long long)fkey(b1) << 32) | (uint32_t)(~i1);
    part[base + 2] = ((unsigned long long)fkey(b2) << 32) | (uint32_t)(~i2);
    part[base + 3] = ((unsigned long long)fkey(b3) << 32) | (uint32_t)(~i3);
}

// A2: reduce chunk partials -> ii[c] (R2-proven config).
__global__ __launch_bounds__(64) void argmax_final(
        const unsigned long long* __restrict__ part,
        int* __restrict__ ii) {
    int c = blockIdx.x * 64 + threadIdx.x;
    unsigned long long best = 0ull;
    #pragma unroll 4
    for (int k = 0; k < CHUNKS; ++k) {
        unsigned long long p = part[(size_t)k * IN_F + c];
        if (p > best) best = p;
    }
    ii[c] = (int)(~(uint32_t)best);
}

// G: persistent gather — 4 rows per block, indices loaded ONCE into registers,
// software-pipelined row staging (load next row to regs while gathering current
// row from LDS). All HBM traffic stays fully coalesced.
__global__ __launch_bounds__(256) void gather_rows(
        const float* __restrict__ x,
        const int* __restrict__ ii,
        float* __restrict__ y) {
    __shared__ float xr[OUT_F];                   // 16 KiB
    int b0 = blockIdx.x * ROWS_PER_BLOCK;

    // indices: thread t owns float4-groups {t, t+256, t+512, t+768}
    const int4* ii4 = (const int4*)ii;
    int4 id[4];
    #pragma unroll
    for (int g = 0; g < 4; ++g) id[g] = ii4[g * 256 + threadIdx.x];

    // prologue: load row 0 into registers
    float4 stg[4];
    {
        const float4* x4 = (const float4*)(x + (size_t)b0 * OUT_F);
        #pragma unroll
        for (int i = 0; i < 4; ++i) stg[i] = x4[i * 256 + threadIdx.x];
    }

    float4* s4 = (float4*)xr;
    for (int r = 0; r < ROWS_PER_BLOCK; ++r) {
        // write staged row to LDS
        #pragma unroll
        for (int i = 0; i < 4; ++i) s4[i * 256 + threadIdx.x] = stg[i];
        __syncthreads();
        // issue next row's loads EARLY — HBM latency hides under the gather
        if (r + 1 < ROWS_PER_BLOCK) {
            const float4* xn = (const float4*)(x + (size_t)(b0 + r + 1) * OUT_F);
            #pragma unroll
            for (int i = 0; i < 4; ++i) stg[i] = xn[i * 256 + threadIdx.x];
        }
        // gather current row from LDS, store coalesced
        float4* y4 = (float4*)(y + (size_t)(b0 + r) * IN_F);
        #pragma unroll
        for (int g = 0; g < 4; ++g) {
            float4 o;
            o.x = xr[id[g].x]; o.y = xr[id[g].y];
            o.z = xr[id[g].z]; o.w = xr[id[g].w];
            y4[g * 256 + threadIdx.x] = o;
        }
        __syncthreads();                          // before overwriting LDS
    }
}

extern "C" void kernel_launch(void* const* d_in, const int* in_sizes, int n_in,
                              void* d_out, int out_size, void* d_ws, size_t ws_size,
                              hipStream_t stream) {
    const float* x = (const float*)d_in[0];       // (BATCH, OUT_F)
    const float* w = (const float*)d_in[1];       // (OUT_F, IN_F)
    float* y = (float*)d_out;                     // (BATCH, IN_F)

    // ws layout: [ part: CHUNKS * IN_F * 8 B = 4 MB ][ ii: IN_F * 4 B ]
    unsigned long long* part = (unsigned long long*)d_ws;
    int* ii = (int*)((char*)d_ws + (size_t)CHUNKS * IN_F * 8);

    dim3 g1(IN_F / (256 * 4), CHUNKS);
    argmax_partial<<<g1, 256, 0, stream>>>(w, part);
    argmax_final<<<IN_F / 64, 64, 0, stream>>>(part, ii);
    gather_rows<<<BATCH / ROWS_PER_BLOCK, 256, 0, stream>>>(x, ii, y);
}

// Round 5
// 56.603 us; speedup vs baseline: 1.7866x; 1.7866x over previous
//
#include <hip/hip_runtime.h>
#include <stdint.h>

#define IN_F   4096   // output width / weight cols
#define OUT_F  4096   // x width / weight rows
#define BATCH  8192
#define CHUNKS 128
#define ROWS_PER_CHUNK (OUT_F / CHUNKS)   // 32

typedef float f4 __attribute__((ext_vector_type(4)));   // for nontemporal builtins

__device__ __forceinline__ uint32_t fkey(float v) {
    // monotone float -> uint mapping (order-preserving for all finite values)
    uint32_t u = __float_as_uint(v);
    return (u & 0x80000000u) ? ~u : (u | 0x80000000u);
}

// A1: partial column-argmax over a 32-row chunk (R2-proven config).
// grid (4, 128), block 256. Each thread owns 4 adjacent columns (float4 loads).
__global__ __launch_bounds__(256) void argmax_partial(
        const float* __restrict__ w,
        unsigned long long* __restrict__ part) {
    int c4 = blockIdx.x * 256 + threadIdx.x;      // float4-column index [0, 1024)
    int r0 = blockIdx.y * ROWS_PER_CHUNK;
    const float4* w4 = (const float4*)w;
    float b0 = -INFINITY, b1 = -INFINITY, b2 = -INFINITY, b3 = -INFINITY;
    int i0 = 0, i1 = 0, i2 = 0, i3 = 0;
    #pragma unroll 8
    for (int k = 0; k < ROWS_PER_CHUNK; ++k) {
        int r = r0 + k;
        float4 v = w4[(size_t)r * (IN_F / 4) + c4];
        if (v.x > b0) { b0 = v.x; i0 = r; }       // '>' keeps FIRST occurrence
        if (v.y > b1) { b1 = v.y; i1 = r; }
        if (v.z > b2) { b2 = v.z; i2 = r; }
        if (v.w > b3) { b3 = v.w; i3 = r; }
    }
    size_t base = (size_t)blockIdx.y * IN_F + (size_t)c4 * 4;
    // pack: key in high 32, ~idx in low 32 -> u64 max == (max val, then min idx)
    part[base + 0] = ((unsigned long long)fkey(b0) << 32) | (uint32_t)(~i0);
    part[base + 1] = ((unsigned long long)fkey(b1) << 32) | (uint32_t)(~i1);
    part[base + 2] = ((unsigned long long)fkey(b2) << 32) | (uint32_t)(~i2);
    part[base + 3] = ((unsigned long long)fkey(b3) << 32) | (uint32_t)(~i3);
}

// A2: reduce chunk partials -> ii. 256 blocks x 256 threads, LDS tree.
// Thread t: column c = blk*16 + (t&15), chunk-slice (t>>4) covers 8 chunks.
// Parallel depth: 8 sequential loads + 4-level LDS tree (vs 128 serial before).
__global__ __launch_bounds__(256) void argmax_final(
        const unsigned long long* __restrict__ part,
        int* __restrict__ ii) {
    __shared__ unsigned long long red[256];
    int t = threadIdx.x;
    int c  = blockIdx.x * 16 + (t & 15);
    int k0 = (t >> 4) * (CHUNKS / 16);
    unsigned long long best = 0ull;
    #pragma unroll
    for (int k = 0; k < CHUNKS / 16; ++k) {
        unsigned long long p = part[(size_t)(k0 + k) * IN_F + c];
        if (p > best) best = p;
    }
    red[t] = best;
    __syncthreads();
    #pragma unroll
    for (int s = 128; s >= 16; s >>= 1) {
        if (t < s && red[t + s] > red[t]) red[t] = red[t + s];
        __syncthreads();
    }
    if (t < 16) ii[blockIdx.x * 16 + t] = (int)(~(uint32_t)red[t]);
}

// G: one row per block (8192 blocks, 16 KiB LDS -> 8 blocks/CU = 32 waves = 100%
// occupancy). One barrier. Non-temporal y stores keep the 128 MB write stream
// from evicting x/w out of L3 (w 64 + x 128 = 192 MB < 256 MB L3).
__global__ __launch_bounds__(256) void gather_rows(
        const float* __restrict__ x,
        const int* __restrict__ ii,
        float* __restrict__ y) {
    __shared__ float xr[OUT_F];                   // 16 KiB
    int b = blockIdx.x;
    const f4* x4 = (const f4*)(x + (size_t)b * OUT_F);
    f4* s4 = (f4*)xr;
    #pragma unroll
    for (int i = 0; i < 4; ++i)                   // coalesced 16 KB stage
        s4[i * 256 + threadIdx.x] = x4[i * 256 + threadIdx.x];
    // index loads (L1/L2-hot, same 16 KB for every block) overlap the stage
    const int4* ii4 = (const int4*)ii;
    int4 id[4];
    #pragma unroll
    for (int g = 0; g < 4; ++g) id[g] = ii4[g * 256 + threadIdx.x];
    __syncthreads();
    f4* y4 = (f4*)(y + (size_t)b * IN_F);
    #pragma unroll
    for (int g = 0; g < 4; ++g) {
        f4 o;
        o.x = xr[id[g].x]; o.y = xr[id[g].y];
        o.z = xr[id[g].z]; o.w = xr[id[g].w];
        __builtin_nontemporal_store(o, &y4[g * 256 + threadIdx.x]);
    }
}

extern "C" void kernel_launch(void* const* d_in, const int* in_sizes, int n_in,
                              void* d_out, int out_size, void* d_ws, size_t ws_size,
                              hipStream_t stream) {
    const float* x = (const float*)d_in[0];       // (BATCH, OUT_F)
    const float* w = (const float*)d_in[1];       // (OUT_F, IN_F)
    float* y = (float*)d_out;                     // (BATCH, IN_F)

    // ws layout: [ part: CHUNKS * IN_F * 8 B = 4 MB ][ ii: IN_F * 4 B ]
    unsigned long long* part = (unsigned long long*)d_ws;
    int* ii = (int*)((char*)d_ws + (size_t)CHUNKS * IN_F * 8);

    dim3 g1(IN_F / (256 * 4), CHUNKS);
    argmax_partial<<<g1, 256, 0, stream>>>(w, part);
    argmax_final<<<IN_F / 16, 256, 0, stream>>>(part, ii);
    gather_rows<<<BATCH, 256, 0, stream>>>(x, ii, y);
}